// Round 2
// baseline (1519.096 us; speedup 1.0000x reference)
//
#include <hip/hip_runtime.h>
#include <hip/hip_bf16.h>
#include <stdint.h>

#define N_EMBD    256
#define N_INPUTS  66
#define N_LEVELS  8
#define APL       4096
#define NPL       2048
#define LVL       6144
#define N_HID     1024

typedef __hip_bfloat16 bf16;
typedef __attribute__((ext_vector_type(8))) short short8;
typedef __attribute__((ext_vector_type(4))) float f32x4;

static __device__ __forceinline__ unsigned short f2b(float f) {
  bf16 h = __float2bfloat16(f);
  return *reinterpret_cast<unsigned short*>(&h);
}

// ---------------- input copy: rows 0..65 of node table ----------------
__global__ void k_copy_inputs(const float* __restrict__ in, float* __restrict__ out) {
  int r = blockIdx.x, t = threadIdx.x;  // 66 blocks x 64 threads
  ((float4*)(out + (size_t)r * 256))[t] = ((const float4*)(in + (size_t)r * 256))[t];
}

// ---------------- transpose + fp32->bf16: out[n*K+k] = bf16(in[k*N+n]) ----------------
// grid (N/32, K/32, batch), block (32,8)
__global__ void k_transpose(const float* __restrict__ in, bf16* __restrict__ out, int K, int N) {
  __shared__ float t[32][33];
  size_t boff = (size_t)blockIdx.z * K * N;
  in += boff; out += boff;
  int n0 = blockIdx.x * 32, k0 = blockIdx.y * 32;
  int tx = threadIdx.x, ty = threadIdx.y;
  #pragma unroll
  for (int j = 0; j < 32; j += 8)
    t[ty + j][tx] = in[(size_t)(k0 + ty + j) * N + n0 + tx];
  __syncthreads();
  #pragma unroll
  for (int j = 0; j < 32; j += 8)
    out[(size_t)(n0 + ty + j) * K + k0 + tx] = __float2bfloat16(t[tx][ty + j]);
}

// ---------------- NOT nodes: node[s+APL+i] = -node[x_edges[s+APL+i]] ----------------
__global__ void k_not(const int* __restrict__ xe, float* __restrict__ node, int s) {
  int i = blockIdx.x;                 // 0..2047
  int dst = s + APL + i;
  int src = xe[dst];
  int t = threadIdx.x;                // 64
  float4 v = ((const float4*)(node + (size_t)src * 256))[t];
  float4 o; o.x = -v.x; o.y = -v.y; o.z = -v.z; o.w = -v.w;
  ((float4*)(node + (size_t)dst * 256))[t] = o;
}

// ---------------- gather concat -> bf16 H0[4096][512] ----------------
__global__ void k_gather(const int* __restrict__ xe, const int* __restrict__ ye,
                         const float* __restrict__ node, bf16* __restrict__ H0, int s) {
  int r = blockIdx.x;                 // 0..4095
  int t = threadIdx.x;                // 64
  int xa = xe[s + r], ya = ye[s + r];
  float4 vx = ((const float4*)(node + (size_t)xa * 256))[t];
  float4 vy = ((const float4*)(node + (size_t)ya * 256))[t];
  ushort4 ox, oy;
  ox.x = f2b(vx.x); ox.y = f2b(vx.y); ox.z = f2b(vx.z); ox.w = f2b(vx.w);
  oy.x = f2b(vy.x); oy.y = f2b(vy.y); oy.z = f2b(vy.z); oy.w = f2b(vy.w);
  bf16* hr = H0 + (size_t)r * 512;
  ((ushort4*)hr)[t] = ox;
  ((ushort4*)(hr + 256))[t] = oy;
}

// ---------------- GEMM: C = act(A[MxK] @ B[KxN] + bias), B given transposed (Bt[N][K]) ----------------
// 128x128 tile, BK=64, 4 waves (2x2) each 64x64, mfma 16x16x32 bf16.
// global_load_lds width 16, XOR-swizzled global source + swizzled ds_read (T2-compatible).
template<bool RELU, bool BF16OUT>
__global__ __launch_bounds__(256, 2)
void k_gemm(const bf16* __restrict__ A, const bf16* __restrict__ Bt,
            const float* __restrict__ bias, void* __restrict__ Cout,
            int M, int N, int K) {
  __shared__ __align__(16) bf16 smem[2 * 128 * 64];
  char* sA = (char*)smem;             // 16384 B (128 rows x 64 bf16)
  char* sB = (char*)smem + 16384;     // 16384 B
  const int tid  = threadIdx.x;
  const int lane = tid & 63;
  const int w    = tid >> 6;
  const int wm   = w >> 1, wn = w & 1;
  const int m0 = blockIdx.x * 128;
  const int n0 = blockIdx.y * 128;

  f32x4 acc[4][4] = {};

  const int nK = K >> 6;
  for (int ks = 0; ks < nK; ++ks) {
    const int k0 = ks << 6;
    __syncthreads();  // previous compute finished before LDS overwrite
    // stage A tile (128 rows x 64 cols bf16 = 1024 x 16B chunks)
    #pragma unroll
    for (int it = 0; it < 4; ++it) {
      int ci = it * 256 + tid;
      int r = ci >> 3, g = ci & 7;
      int gs = g ^ (r & 7);  // pre-swizzled source colgroup
      const bf16* ga = A + (size_t)(m0 + r) * K + k0 + gs * 8;
      char* la = sA + (it * 256 + w * 64) * 16;  // wave-uniform base
      __builtin_amdgcn_global_load_lds((const __attribute__((address_space(1))) void*)ga,
                                       (__attribute__((address_space(3))) void*)la, 16, 0, 0);
    }
    // stage B tile (128 Bt-rows x 64 cols)
    #pragma unroll
    for (int it = 0; it < 4; ++it) {
      int ci = it * 256 + tid;
      int r = ci >> 3, g = ci & 7;
      int gs = g ^ (r & 7);
      const bf16* gb = Bt + (size_t)(n0 + r) * K + k0 + gs * 8;
      char* lb = sB + (it * 256 + w * 64) * 16;
      __builtin_amdgcn_global_load_lds((const __attribute__((address_space(1))) void*)gb,
                                       (__attribute__((address_space(3))) void*)lb, 16, 0, 0);
    }
    __syncthreads();  // compiler drains vmcnt(0) before barrier

    #pragma unroll
    for (int kk = 0; kk < 2; ++kk) {
      short8 af[4], bfr[4];
      #pragma unroll
      for (int mt = 0; mt < 4; ++mt) {
        int row = wm * 64 + mt * 16 + (lane & 15);
        int g = kk * 4 + (lane >> 4);
        af[mt] = *(const short8*)(sA + row * 128 + ((g ^ (row & 7)) * 16));
      }
      #pragma unroll
      for (int nt = 0; nt < 4; ++nt) {
        int row = wn * 64 + nt * 16 + (lane & 15);
        int g = kk * 4 + (lane >> 4);
        bfr[nt] = *(const short8*)(sB + row * 128 + ((g ^ (row & 7)) * 16));
      }
      #pragma unroll
      for (int mt = 0; mt < 4; ++mt)
        #pragma unroll
        for (int nt = 0; nt < 4; ++nt)
          acc[mt][nt] = __builtin_amdgcn_mfma_f32_16x16x32_bf16(af[mt], bfr[nt], acc[mt][nt], 0, 0, 0);
    }
  }

  // epilogue: bias + optional relu, bf16 or fp32 store
  #pragma unroll
  for (int nt = 0; nt < 4; ++nt) {
    int col = n0 + wn * 64 + nt * 16 + (lane & 15);
    float bv = bias[col];
    #pragma unroll
    for (int mt = 0; mt < 4; ++mt) {
      int rbase = m0 + wm * 64 + mt * 16 + (lane >> 4) * 4;
      #pragma unroll
      for (int r = 0; r < 4; ++r) {
        float v = acc[mt][nt][r] + bv;
        if (RELU) v = fmaxf(v, 0.f);
        if (BF16OUT)
          ((unsigned short*)Cout)[(size_t)(rbase + r) * N + col] = f2b(v);
        else
          ((float*)Cout)[(size_t)(rbase + r) * N + col] = v;
      }
    }
  }
}

// ---------------- LayerNorm rows of X[4096][256] -> node[s..s+4095] ----------------
__global__ void k_ln(const float* __restrict__ X, const float* __restrict__ g,
                     const float* __restrict__ b, float* __restrict__ node, int s) {
  int r = blockIdx.x;   // 0..4095
  int t = threadIdx.x;  // 64
  float4 x = ((const float4*)(X + (size_t)r * 256))[t];
  float sm = x.x + x.y + x.z + x.w;
  float sq = x.x * x.x + x.y * x.y + x.z * x.z + x.w * x.w;
  #pragma unroll
  for (int o = 1; o < 64; o <<= 1) { sm += __shfl_xor(sm, o); sq += __shfl_xor(sq, o); }
  float mu  = sm * (1.f / 256.f);
  float var = sq * (1.f / 256.f) - mu * mu;
  float rs  = rsqrtf(var + 1e-5f);
  float4 gv = ((const float4*)g)[t], bv = ((const float4*)b)[t];
  float4 o4;
  o4.x = (x.x - mu) * rs * gv.x + bv.x;
  o4.y = (x.y - mu) * rs * gv.y + bv.y;
  o4.z = (x.z - mu) * rs * gv.z + bv.z;
  o4.w = (x.w - mu) * rs * gv.w + bv.w;
  ((float4*)(node + (size_t)(s + r) * 256))[t] = o4;
}

extern "C" void kernel_launch(void* const* d_in, const int* in_sizes, int n_in,
                              void* d_out, int out_size, void* d_ws, size_t ws_size,
                              hipStream_t stream) {
  const int*   x_edges    = (const int*)d_in[1];
  const int*   y_edges    = (const int*)d_in[2];
  const float* input_embd = (const float*)d_in[3];
  const float* W_in       = (const float*)d_in[4];
  const float* b_in       = (const float*)d_in[5];
  const float* W_hid      = (const float*)d_in[6];
  const float* b_hid      = (const float*)d_in[7];
  const float* W_out      = (const float*)d_in[8];
  const float* b_out      = (const float*)d_in[9];
  const float* ln_g       = (const float*)d_in[10];
  const float* ln_b       = (const float*)d_in[11];
  float* node = (float*)d_out;

  char* ws = (char*)d_ws;
  bf16* WtIn  = (bf16*)(ws);                                   // 1024x512
  bf16* WtHid = (bf16*)(ws + (size_t)1048576);                 // 8x1024x1024
  bf16* WtOut = (bf16*)(ws + (size_t)17825792);                // 256x1024
  bf16* H0    = (bf16*)(ws + (size_t)18350080);                // 4096x512
  bf16* HA    = (bf16*)(ws + (size_t)22544384);                // 4096x1024
  bf16* HB    = (bf16*)(ws + (size_t)30932992);                // 4096x1024
  float* OutF = (float*)HB;                                    // reuse (4096x256 f32)

  // node rows 0..65 = input embeddings
  k_copy_inputs<<<dim3(66), dim3(64), 0, stream>>>(input_embd, node);

  // weights -> bf16 transposed
  k_transpose<<<dim3(1024 / 32, 512 / 32, 1), dim3(32, 8), 0, stream>>>(W_in, WtIn, 512, 1024);
  k_transpose<<<dim3(1024 / 32, 1024 / 32, 8), dim3(32, 8), 0, stream>>>(W_hid, WtHid, 1024, 1024);
  k_transpose<<<dim3(256 / 32, 1024 / 32, 1), dim3(32, 8), 0, stream>>>(W_out, WtOut, 1024, 256);

  for (int l = 0; l < N_LEVELS; ++l) {
    int s = N_INPUTS + l * LVL;
    k_not<<<dim3(NPL), dim3(64), 0, stream>>>(x_edges, node, s);
    k_gather<<<dim3(APL), dim3(64), 0, stream>>>(x_edges, y_edges, node, H0, s);

    // MLP
    k_gemm<true, true><<<dim3(32, 8), dim3(256), 0, stream>>>(H0, WtIn, b_in, HA, 4096, 1024, 512);
    const bf16* src = HA; bf16* dst = HB;
    for (int i = 0; i < 8; ++i) {
      k_gemm<true, true><<<dim3(32, 8), dim3(256), 0, stream>>>(
          src, WtHid + (size_t)i * 1024 * 1024, b_hid + i * 1024, dst, 4096, 1024, 1024);
      const bf16* tmp = src; src = dst; dst = (bf16*)tmp;
    }
    // src == HA here; write fp32 MLP output into OutF (= HB space, no longer needed)
    k_gemm<false, false><<<dim3(32, 2), dim3(256), 0, stream>>>(src, WtOut, b_out, OutF, 4096, 256, 1024);

    k_ln<<<dim3(APL), dim3(64), 0, stream>>>(OutF, ln_g, ln_b, node, s);
  }
}

// Round 3
// 1100.130 us; speedup vs baseline: 1.3808x; 1.3808x over previous
//
#include <hip/hip_runtime.h>
#include <hip/hip_bf16.h>
#include <stdint.h>

#define N_EMBD    256
#define N_INPUTS  66
#define N_LEVELS  8
#define APL       4096
#define NPL       2048
#define LVL       6144
#define N_HID     1024

typedef __hip_bfloat16 bf16;
typedef __attribute__((ext_vector_type(8))) short short8;
typedef __attribute__((ext_vector_type(4))) float f32x4;

static __device__ __forceinline__ unsigned short f2b(float f) {
  bf16 h = __float2bfloat16(f);
  return *reinterpret_cast<unsigned short*>(&h);
}

// ---------------- input copy: rows 0..65 of node table ----------------
__global__ void k_copy_inputs(const float* __restrict__ in, float* __restrict__ out) {
  int r = blockIdx.x, t = threadIdx.x;  // 66 blocks x 64 threads
  ((float4*)(out + (size_t)r * 256))[t] = ((const float4*)(in + (size_t)r * 256))[t];
}

// ---------------- transpose + fp32->bf16: out[n*K+k] = bf16(in[k*N+n]) ----------------
// grid (N/32, K/32, batch), block (32,8)
__global__ void k_transpose(const float* __restrict__ in, bf16* __restrict__ out, int K, int N) {
  __shared__ float t[32][33];
  size_t boff = (size_t)blockIdx.z * K * N;
  in += boff; out += boff;
  int n0 = blockIdx.x * 32, k0 = blockIdx.y * 32;
  int tx = threadIdx.x, ty = threadIdx.y;
  #pragma unroll
  for (int j = 0; j < 32; j += 8)
    t[ty + j][tx] = in[(size_t)(k0 + ty + j) * N + n0 + tx];
  __syncthreads();
  #pragma unroll
  for (int j = 0; j < 32; j += 8)
    out[(size_t)(n0 + ty + j) * K + k0 + tx] = __float2bfloat16(t[tx][ty + j]);
}

// ---------------- NOT nodes: node[s+APL+i] = -node[x_edges[s+APL+i]] ----------------
__global__ void k_not(const int* __restrict__ xe, float* __restrict__ node, int s) {
  int i = blockIdx.x;                 // 0..2047
  int dst = s + APL + i;
  int src = xe[dst];
  int t = threadIdx.x;                // 64
  float4 v = ((const float4*)(node + (size_t)src * 256))[t];
  float4 o; o.x = -v.x; o.y = -v.y; o.z = -v.z; o.w = -v.w;
  ((float4*)(node + (size_t)dst * 256))[t] = o;
}

// ---------------- gather concat -> bf16 H0[4096][512] ----------------
__global__ void k_gather(const int* __restrict__ xe, const int* __restrict__ ye,
                         const float* __restrict__ node, bf16* __restrict__ H0, int s) {
  int r = blockIdx.x;                 // 0..4095
  int t = threadIdx.x;                // 64
  int xa = xe[s + r], ya = ye[s + r];
  float4 vx = ((const float4*)(node + (size_t)xa * 256))[t];
  float4 vy = ((const float4*)(node + (size_t)ya * 256))[t];
  ushort4 ox, oy;
  ox.x = f2b(vx.x); ox.y = f2b(vx.y); ox.z = f2b(vx.z); ox.w = f2b(vx.w);
  oy.x = f2b(vy.x); oy.y = f2b(vy.y); oy.z = f2b(vy.z); oy.w = f2b(vy.w);
  bf16* hr = H0 + (size_t)r * 512;
  ((ushort4*)hr)[t] = ox;
  ((ushort4*)(hr + 256))[t] = oy;
}

// ---------------- GEMM: C = act(A[MxK] @ B[KxN] + bias), Bt[N][K] ----------------
// BM x BN tile, BK=64, 4 waves (2x2), each wave (BM/2)x(BN/2), mfma 16x16x32 bf16.
// Double-buffered LDS, 2-phase pipeline (stage next || compute cur, 1 barrier/K-step).
// global_load_lds width 16, XOR-swizzle applied on global SOURCE + on ds_read (rule #21).
template<int BM, int BN, bool RELU, bool BF16OUT>
__global__ __launch_bounds__(256, 2)
void k_gemm(const bf16* __restrict__ A, const bf16* __restrict__ Bt,
            const float* __restrict__ bias, void* __restrict__ Cout,
            int M, int N, int K) {
  constexpr int MT = BM / 32;            // A-frags per wave
  constexpr int NT = BN / 32;            // B-frags per wave
  constexpr int ABYTES = BM * 128;       // BM rows x 64 bf16
  constexpr int BBYTES = BN * 128;
  constexpr int BUF = ABYTES + BBYTES;
  __shared__ __align__(16) char smem[2 * BUF];

  const int tid  = threadIdx.x;
  const int lane = tid & 63;
  const int w    = tid >> 6;
  const int wm   = w >> 1, wn = w & 1;
  const int m0 = blockIdx.x * BM;
  const int n0 = blockIdx.y * BN;

  f32x4 acc[MT][NT] = {};

  auto STAGE = [&](char* base, int ks) {
    const int k0 = ks << 6;
    char* sA = base;
    char* sB = base + ABYTES;
    #pragma unroll
    for (int it = 0; it < BM / 32; ++it) {
      int ci = it * 256 + tid;
      int r = ci >> 3, g = ci & 7;
      int gs = g ^ (r & 7);  // pre-swizzled source colgroup
      const bf16* ga = A + (size_t)(m0 + r) * K + k0 + gs * 8;
      char* la = sA + (it * 256 + w * 64) * 16;  // wave-uniform base + lane*16
      __builtin_amdgcn_global_load_lds((const __attribute__((address_space(1))) void*)ga,
                                       (__attribute__((address_space(3))) void*)la, 16, 0, 0);
    }
    #pragma unroll
    for (int it = 0; it < BN / 32; ++it) {
      int ci = it * 256 + tid;
      int r = ci >> 3, g = ci & 7;
      int gs = g ^ (r & 7);
      const bf16* gb = Bt + (size_t)(n0 + r) * K + k0 + gs * 8;
      char* lb = sB + (it * 256 + w * 64) * 16;
      __builtin_amdgcn_global_load_lds((const __attribute__((address_space(1))) void*)gb,
                                       (__attribute__((address_space(3))) void*)lb, 16, 0, 0);
    }
  };

  const int nK = K >> 6;
  STAGE(smem, 0);
  __syncthreads();  // vmcnt(0) drain + barrier: buf0 ready

  int cur = 0;
  for (int ks = 0; ks < nK; ++ks) {
    char* cbase = smem + cur * BUF;
    char* nbase = smem + (cur ^ 1) * BUF;
    if (ks + 1 < nK) STAGE(nbase, ks + 1);  // issue next-tile loads first

    char* sA = cbase;
    char* sB = cbase + ABYTES;
    #pragma unroll
    for (int kk = 0; kk < 2; ++kk) {
      short8 af[MT], bfr[NT];
      #pragma unroll
      for (int mt = 0; mt < MT; ++mt) {
        int row = wm * (BM / 2) + mt * 16 + (lane & 15);
        int g = kk * 4 + (lane >> 4);
        af[mt] = *(const short8*)(sA + row * 128 + ((g ^ (row & 7)) * 16));
      }
      #pragma unroll
      for (int nt = 0; nt < NT; ++nt) {
        int row = wn * (BN / 2) + nt * 16 + (lane & 15);
        int g = kk * 4 + (lane >> 4);
        bfr[nt] = *(const short8*)(sB + row * 128 + ((g ^ (row & 7)) * 16));
      }
      #pragma unroll
      for (int mt = 0; mt < MT; ++mt)
        #pragma unroll
        for (int nt = 0; nt < NT; ++nt)
          acc[mt][nt] = __builtin_amdgcn_mfma_f32_16x16x32_bf16(af[mt], bfr[nt], acc[mt][nt], 0, 0, 0);
    }
    __syncthreads();  // drains vmcnt(0) (next stage) + lgkmcnt; barrier
    cur ^= 1;
  }

  // epilogue: bias + optional relu, bf16 or fp32 store
  #pragma unroll
  for (int nt = 0; nt < NT; ++nt) {
    int col = n0 + wn * (BN / 2) + nt * 16 + (lane & 15);
    float bv = bias[col];
    #pragma unroll
    for (int mt = 0; mt < MT; ++mt) {
      int rbase = m0 + wm * (BM / 2) + mt * 16 + (lane >> 4) * 4;
      #pragma unroll
      for (int r = 0; r < 4; ++r) {
        float v = acc[mt][nt][r] + bv;
        if (RELU) v = fmaxf(v, 0.f);
        if (BF16OUT)
          ((unsigned short*)Cout)[(size_t)(rbase + r) * N + col] = f2b(v);
        else
          ((float*)Cout)[(size_t)(rbase + r) * N + col] = v;
      }
    }
  }
}

// ---------------- LayerNorm rows of X[4096][256] -> node[s..s+4095] ----------------
__global__ void k_ln(const float* __restrict__ X, const float* __restrict__ g,
                     const float* __restrict__ b, float* __restrict__ node, int s) {
  int r = blockIdx.x;   // 0..4095
  int t = threadIdx.x;  // 64
  float4 x = ((const float4*)(X + (size_t)r * 256))[t];
  float sm = x.x + x.y + x.z + x.w;
  float sq = x.x * x.x + x.y * x.y + x.z * x.z + x.w * x.w;
  #pragma unroll
  for (int o = 1; o < 64; o <<= 1) { sm += __shfl_xor(sm, o); sq += __shfl_xor(sq, o); }
  float mu  = sm * (1.f / 256.f);
  float var = sq * (1.f / 256.f) - mu * mu;
  float rs  = rsqrtf(var + 1e-5f);
  float4 gv = ((const float4*)g)[t], bv = ((const float4*)b)[t];
  float4 o4;
  o4.x = (x.x - mu) * rs * gv.x + bv.x;
  o4.y = (x.y - mu) * rs * gv.y + bv.y;
  o4.z = (x.z - mu) * rs * gv.z + bv.z;
  o4.w = (x.w - mu) * rs * gv.w + bv.w;
  ((float4*)(node + (size_t)(s + r) * 256))[t] = o4;
}

extern "C" void kernel_launch(void* const* d_in, const int* in_sizes, int n_in,
                              void* d_out, int out_size, void* d_ws, size_t ws_size,
                              hipStream_t stream) {
  const int*   x_edges    = (const int*)d_in[1];
  const int*   y_edges    = (const int*)d_in[2];
  const float* input_embd = (const float*)d_in[3];
  const float* W_in       = (const float*)d_in[4];
  const float* b_in       = (const float*)d_in[5];
  const float* W_hid      = (const float*)d_in[6];
  const float* b_hid      = (const float*)d_in[7];
  const float* W_out      = (const float*)d_in[8];
  const float* b_out      = (const float*)d_in[9];
  const float* ln_g       = (const float*)d_in[10];
  const float* ln_b       = (const float*)d_in[11];
  float* node = (float*)d_out;

  char* ws = (char*)d_ws;
  bf16* WtIn  = (bf16*)(ws);                                   // 1024x512
  bf16* WtHid = (bf16*)(ws + (size_t)1048576);                 // 8x1024x1024
  bf16* WtOut = (bf16*)(ws + (size_t)17825792);                // 256x1024
  bf16* H0    = (bf16*)(ws + (size_t)18350080);                // 4096x512
  bf16* HA    = (bf16*)(ws + (size_t)22544384);                // 4096x1024
  bf16* HB    = (bf16*)(ws + (size_t)30932992);                // 4096x1024
  float* OutF = (float*)HB;                                    // reuse (4096x256 f32)

  // node rows 0..65 = input embeddings
  k_copy_inputs<<<dim3(66), dim3(64), 0, stream>>>(input_embd, node);

  // weights -> bf16 transposed
  k_transpose<<<dim3(1024 / 32, 512 / 32, 1), dim3(32, 8), 0, stream>>>(W_in, WtIn, 512, 1024);
  k_transpose<<<dim3(1024 / 32, 1024 / 32, 8), dim3(32, 8), 0, stream>>>(W_hid, WtHid, 1024, 1024);
  k_transpose<<<dim3(256 / 32, 1024 / 32, 1), dim3(32, 8), 0, stream>>>(W_out, WtOut, 1024, 256);

  for (int l = 0; l < N_LEVELS; ++l) {
    int s = N_INPUTS + l * LVL;
    k_not<<<dim3(NPL), dim3(64), 0, stream>>>(x_edges, node, s);
    k_gather<<<dim3(APL), dim3(64), 0, stream>>>(x_edges, y_edges, node, H0, s);

    // MLP: 128x64 tiles -> 512 blocks (2/CU)
    k_gemm<128, 64, true, true><<<dim3(32, 16), dim3(256), 0, stream>>>(H0, WtIn, b_in, HA, 4096, 1024, 512);
    const bf16* src = HA; bf16* dst = HB;
    for (int i = 0; i < 8; ++i) {
      k_gemm<128, 64, true, true><<<dim3(32, 16), dim3(256), 0, stream>>>(
          src, WtHid + (size_t)i * 1024 * 1024, b_hid + i * 1024, dst, 4096, 1024, 1024);
      const bf16* tmp = src; src = dst; dst = (bf16*)tmp;
    }
    // src == HA here; fp32 MLP output into OutF (= HB space, no longer needed)
    k_gemm<64, 64, false, false><<<dim3(64, 4), dim3(256), 0, stream>>>(src, WtOut, b_out, OutF, 4096, 256, 1024);

    k_ln<<<dim3(APL), dim3(64), 0, stream>>>(OutF, ln_g, ln_b, node, s);
  }
}

// Round 4
// 958.877 us; speedup vs baseline: 1.5842x; 1.1473x over previous
//
#include <hip/hip_runtime.h>
#include <hip/hip_bf16.h>
#include <stdint.h>

#define N_EMBD    256
#define N_INPUTS  66
#define N_LEVELS  8
#define APL       4096
#define NPL       2048
#define LVL       6144
#define N_HID     1024

typedef __hip_bfloat16 bf16;
typedef __attribute__((ext_vector_type(8))) short short8;
typedef __attribute__((ext_vector_type(4))) float f32x4;

static __device__ __forceinline__ unsigned short f2b(float f) {
  bf16 h = __float2bfloat16(f);
  return *reinterpret_cast<unsigned short*>(&h);
}

// ---------------- input copy: rows 0..65 of node table ----------------
__global__ void k_copy_inputs(const float* __restrict__ in, float* __restrict__ out) {
  int r = blockIdx.x, t = threadIdx.x;  // 66 blocks x 64 threads
  ((float4*)(out + (size_t)r * 256))[t] = ((const float4*)(in + (size_t)r * 256))[t];
}

// ---------------- transpose + fp32->bf16: out[n*K+k] = bf16(in[k*N+n]) ----------------
__global__ void k_transpose(const float* __restrict__ in, bf16* __restrict__ out, int K, int N) {
  __shared__ float t[32][33];
  size_t boff = (size_t)blockIdx.z * K * N;
  in += boff; out += boff;
  int n0 = blockIdx.x * 32, k0 = blockIdx.y * 32;
  int tx = threadIdx.x, ty = threadIdx.y;
  #pragma unroll
  for (int j = 0; j < 32; j += 8)
    t[ty + j][tx] = in[(size_t)(k0 + ty + j) * N + n0 + tx];
  __syncthreads();
  #pragma unroll
  for (int j = 0; j < 32; j += 8)
    out[(size_t)(n0 + ty + j) * K + k0 + tx] = __float2bfloat16(t[tx][ty + j]);
}

// ---------------- fused NOT + gather (independent within a level) ----------------
// blocks [0, NPL): NOT row i -> node[s+APL+i] = -node[xe[...]]
// blocks [NPL, NPL+APL): AND row r -> H0[r] = bf16(concat(node[xa], node[ya]))
__global__ void k_not_gather(const int* __restrict__ xe, const int* __restrict__ ye,
                             float* __restrict__ node, bf16* __restrict__ H0, int s) {
  int b = blockIdx.x, t = threadIdx.x;  // 64 threads
  if (b < NPL) {
    int dst = s + APL + b;
    int src = xe[dst];
    float4 v = ((const float4*)(node + (size_t)src * 256))[t];
    float4 o; o.x = -v.x; o.y = -v.y; o.z = -v.z; o.w = -v.w;
    ((float4*)(node + (size_t)dst * 256))[t] = o;
  } else {
    int r = b - NPL;
    int xa = xe[s + r], ya = ye[s + r];
    float4 vx = ((const float4*)(node + (size_t)xa * 256))[t];
    float4 vy = ((const float4*)(node + (size_t)ya * 256))[t];
    ushort4 ox, oy;
    ox.x = f2b(vx.x); ox.y = f2b(vx.y); ox.z = f2b(vx.z); ox.w = f2b(vx.w);
    oy.x = f2b(vy.x); oy.y = f2b(vy.y); oy.z = f2b(vy.z); oy.w = f2b(vy.w);
    bf16* hr = H0 + (size_t)r * 512;
    ((ushort4*)hr)[t] = ox;
    ((ushort4*)(hr + 256))[t] = oy;
  }
}

// ---------------- GEMM: C = act(A[MxK] @ B[KxN] + bias), Bt[N][K] ----------------
// BM x BN tile, BK=64, 4 waves (2x2), each wave (BM/2)x(BN/2), mfma 16x16x32 bf16.
// 2-deep counted-vmcnt pipeline (T4): STAGE(ks) and STAGE(ks+1) in flight; per iter
// wait vmcnt(LOADS) (not 0) -> each load batch has 2 compute phases of latency cover.
// global_load_lds width 16, XOR-swizzle on global SOURCE + on ds_read (rule #21).
template<int BM, int BN, bool RELU, bool BF16OUT>
__global__ __launch_bounds__(256, 2)
void k_gemm(const bf16* __restrict__ A, const bf16* __restrict__ Bt,
            const float* __restrict__ bias, void* __restrict__ Cout,
            int M, int N, int K) {
  constexpr int MT = BM / 32;            // A-frags per wave (wave owns BM/2 rows)
  constexpr int NT = BN / 32;
  constexpr int ABYTES = BM * 128;       // BM rows x 64 bf16
  constexpr int BBYTES = BN * 128;
  constexpr int BUF = ABYTES + BBYTES;
  constexpr int LOADS = BM / 32 + BN / 32;  // global_load_lds per thread per STAGE
  __shared__ __align__(16) char smem[2 * BUF];

  const int tid  = threadIdx.x;
  const int lane = tid & 63;
  const int w    = tid >> 6;
  const int wm   = w >> 1, wn = w & 1;
  const int m0 = blockIdx.x * BM;
  const int n0 = blockIdx.y * BN;

  f32x4 acc[MT][NT] = {};

  auto STAGE = [&](char* base, int ks) {
    const int k0 = ks << 6;
    char* sA = base;
    char* sB = base + ABYTES;
    #pragma unroll
    for (int it = 0; it < BM / 32; ++it) {
      int ci = it * 256 + tid;
      int r = ci >> 3, g = ci & 7;
      int gs = g ^ (r & 7);  // pre-swizzled source colgroup
      const bf16* ga = A + (size_t)(m0 + r) * K + k0 + gs * 8;
      char* la = sA + (it * 256 + w * 64) * 16;  // wave-uniform base + lane*16
      __builtin_amdgcn_global_load_lds((const __attribute__((address_space(1))) void*)ga,
                                       (__attribute__((address_space(3))) void*)la, 16, 0, 0);
    }
    #pragma unroll
    for (int it = 0; it < BN / 32; ++it) {
      int ci = it * 256 + tid;
      int r = ci >> 3, g = ci & 7;
      int gs = g ^ (r & 7);
      const bf16* gb = Bt + (size_t)(n0 + r) * K + k0 + gs * 8;
      char* lb = sB + (it * 256 + w * 64) * 16;
      __builtin_amdgcn_global_load_lds((const __attribute__((address_space(1))) void*)gb,
                                       (__attribute__((address_space(3))) void*)lb, 16, 0, 0);
    }
  };

  const int nK = K >> 6;
  STAGE(smem, 0);
  if (1 < nK) STAGE(smem + BUF, 1);

  for (int ks = 0; ks < nK; ++ks) {
    // wait: STAGE(ks) complete; STAGE(ks+1) (LOADS newest) may stay in flight
    if (ks + 1 < nK) {
      if constexpr (LOADS == 6)      asm volatile("s_waitcnt vmcnt(6)" ::: "memory");
      else if constexpr (LOADS == 4) asm volatile("s_waitcnt vmcnt(4)" ::: "memory");
      else                           asm volatile("s_waitcnt vmcnt(0)" ::: "memory");
    } else {
      asm volatile("s_waitcnt vmcnt(0)" ::: "memory");
    }
    __builtin_amdgcn_s_barrier();  // all waves' tile-ks loads landed

    char* sA = smem + (ks & 1) * BUF;
    char* sB = sA + ABYTES;
    #pragma unroll
    for (int kk = 0; kk < 2; ++kk) {
      short8 af[MT], bfr[NT];
      #pragma unroll
      for (int mt = 0; mt < MT; ++mt) {
        int row = wm * (BM / 2) + mt * 16 + (lane & 15);
        int g = kk * 4 + (lane >> 4);
        af[mt] = *(const short8*)(sA + row * 128 + ((g ^ (row & 7)) * 16));
      }
      #pragma unroll
      for (int nt = 0; nt < NT; ++nt) {
        int row = wn * (BN / 2) + nt * 16 + (lane & 15);
        int g = kk * 4 + (lane >> 4);
        bfr[nt] = *(const short8*)(sB + row * 128 + ((g ^ (row & 7)) * 16));
      }
      #pragma unroll
      for (int mt = 0; mt < MT; ++mt)
        #pragma unroll
        for (int nt = 0; nt < NT; ++nt)
          acc[mt][nt] = __builtin_amdgcn_mfma_f32_16x16x32_bf16(af[mt], bfr[nt], acc[mt][nt], 0, 0, 0);
    }
    __builtin_amdgcn_s_barrier();  // all waves done reading buf (ks&1)
    if (ks + 2 < nK) STAGE(smem + (ks & 1) * BUF, ks + 2);
  }

  // epilogue: bias + optional relu, bf16 or fp32 store
  #pragma unroll
  for (int nt = 0; nt < NT; ++nt) {
    int col = n0 + wn * (BN / 2) + nt * 16 + (lane & 15);
    float bv = bias[col];
    #pragma unroll
    for (int mt = 0; mt < MT; ++mt) {
      int rbase = m0 + wm * (BM / 2) + mt * 16 + (lane >> 4) * 4;
      #pragma unroll
      for (int r = 0; r < 4; ++r) {
        float v = acc[mt][nt][r] + bv;
        if (RELU) v = fmaxf(v, 0.f);
        if (BF16OUT)
          ((unsigned short*)Cout)[(size_t)(rbase + r) * N + col] = f2b(v);
        else
          ((float*)Cout)[(size_t)(rbase + r) * N + col] = v;
      }
    }
  }
}

// ---------------- LayerNorm rows of X[4096][256] -> node[s..s+4095] ----------------
__global__ void k_ln(const float* __restrict__ X, const float* __restrict__ g,
                     const float* __restrict__ b, float* __restrict__ node, int s) {
  int r = blockIdx.x;   // 0..4095
  int t = threadIdx.x;  // 64
  float4 x = ((const float4*)(X + (size_t)r * 256))[t];
  float sm = x.x + x.y + x.z + x.w;
  float sq = x.x * x.x + x.y * x.y + x.z * x.z + x.w * x.w;
  #pragma unroll
  for (int o = 1; o < 64; o <<= 1) { sm += __shfl_xor(sm, o); sq += __shfl_xor(sq, o); }
  float mu  = sm * (1.f / 256.f);
  float var = sq * (1.f / 256.f) - mu * mu;
  float rs  = rsqrtf(var + 1e-5f);
  float4 gv = ((const float4*)g)[t], bv = ((const float4*)b)[t];
  float4 o4;
  o4.x = (x.x - mu) * rs * gv.x + bv.x;
  o4.y = (x.y - mu) * rs * gv.y + bv.y;
  o4.z = (x.z - mu) * rs * gv.z + bv.z;
  o4.w = (x.w - mu) * rs * gv.w + bv.w;
  ((float4*)(node + (size_t)(s + r) * 256))[t] = o4;
}

extern "C" void kernel_launch(void* const* d_in, const int* in_sizes, int n_in,
                              void* d_out, int out_size, void* d_ws, size_t ws_size,
                              hipStream_t stream) {
  const int*   x_edges    = (const int*)d_in[1];
  const int*   y_edges    = (const int*)d_in[2];
  const float* input_embd = (const float*)d_in[3];
  const float* W_in       = (const float*)d_in[4];
  const float* b_in       = (const float*)d_in[5];
  const float* W_hid      = (const float*)d_in[6];
  const float* b_hid      = (const float*)d_in[7];
  const float* W_out      = (const float*)d_in[8];
  const float* b_out      = (const float*)d_in[9];
  const float* ln_g       = (const float*)d_in[10];
  const float* ln_b       = (const float*)d_in[11];
  float* node = (float*)d_out;

  char* ws = (char*)d_ws;
  bf16* WtIn  = (bf16*)(ws);                                   // 1024x512
  bf16* WtHid = (bf16*)(ws + (size_t)1048576);                 // 8x1024x1024
  bf16* WtOut = (bf16*)(ws + (size_t)17825792);                // 256x1024
  bf16* H0    = (bf16*)(ws + (size_t)18350080);                // 4096x512
  bf16* HA    = (bf16*)(ws + (size_t)22544384);                // 4096x1024
  bf16* HB    = (bf16*)(ws + (size_t)30932992);                // 4096x1024
  float* OutF = (float*)HB;                                    // reuse (4096x256 f32)

  // node rows 0..65 = input embeddings
  k_copy_inputs<<<dim3(66), dim3(64), 0, stream>>>(input_embd, node);

  // weights -> bf16 transposed
  k_transpose<<<dim3(1024 / 32, 512 / 32, 1), dim3(32, 8), 0, stream>>>(W_in, WtIn, 512, 1024);
  k_transpose<<<dim3(1024 / 32, 1024 / 32, 8), dim3(32, 8), 0, stream>>>(W_hid, WtHid, 1024, 1024);
  k_transpose<<<dim3(256 / 32, 1024 / 32, 1), dim3(32, 8), 0, stream>>>(W_out, WtOut, 1024, 256);

  for (int l = 0; l < N_LEVELS; ++l) {
    int s = N_INPUTS + l * LVL;
    k_not_gather<<<dim3(NPL + APL), dim3(64), 0, stream>>>(x_edges, y_edges, node, H0, s);

    // MLP: 128x64 tiles -> 512 blocks (2/CU)
    k_gemm<128, 64, true, true><<<dim3(32, 16), dim3(256), 0, stream>>>(H0, WtIn, b_in, HA, 4096, 1024, 512);
    const bf16* src = HA; bf16* dst = HB;
    for (int i = 0; i < 8; ++i) {
      k_gemm<128, 64, true, true><<<dim3(32, 16), dim3(256), 0, stream>>>(
          src, WtHid + (size_t)i * 1024 * 1024, b_hid + i * 1024, dst, 4096, 1024, 1024);
      const bf16* tmp = src; src = dst; dst = (bf16*)tmp;
    }
    // src == HA here; fp32 MLP output into OutF (= HB space, no longer needed)
    k_gemm<64, 64, false, false><<<dim3(64, 4), dim3(256), 0, stream>>>(src, WtOut, b_out, OutF, 4096, 256, 1024);

    k_ln<<<dim3(APL), dim3(64), 0, stream>>>(OutF, ln_g, ln_b, node, s);
  }
}